// Round 13
// baseline (179.317 us; speedup 1.0000x reference)
//
#include <hip/hip_runtime.h>

typedef _Float16 f16;
typedef _Float16 f16x2 __attribute__((ext_vector_type(2)));
typedef _Float16 f16x4 __attribute__((ext_vector_type(4)));
typedef _Float16 f16x8 __attribute__((ext_vector_type(8)));
typedef float    f32x4 __attribute__((ext_vector_type(4)));

// Geometry:
//   x:   (4,128,64,64) f32     p5: (128,21,64,64) f32
//   p6:  (128,21,128)  f32     out:(4,128,64,64)  f32
// Workspace (~73.8 MB):
//   xk   [3kc][4n][128c][82row][64w] f16 = x/8, w-inner          (gram operands)
//   xkTg [4g][3kc][4n][82row][64w][32c] f16 = x/8, g-major c-inner (outp A)
//   q5Tg [4g][21rk][64h][64w][32c] f16 = 1+p5, g-major c-inner     (outp A)
//   t6T  [4n][128d][2688] f16 = p6 * t3, d-major                   (outp B)
//   t3p  [8ks][4n][11rki][128c][128d] f16 = split-K Gram partials (rki 0..10;
//        t3[c,rk,d] = t3[d,20-rk,c] exactly — lag symmetry; ep mirrors rk>=11)
//   t8p  [4g][4n][64h][128d][64w] f16 = split-K out partials, ALIASES t3p
#define XROWS 82
#define XSTR  (XROWS * 64)
static const size_t XK_OFF  = 0;                                   // 16,121,856
static const size_t XKT_OFF = 16121856;                            // 16,121,856
static const size_t Q5T_OFF = XKT_OFF + 16121856;                  // 22,020,096
static const size_t T6T_OFF = Q5T_OFF + 22020096;                  //  2,752,512
static const size_t T3P_OFF = T6T_OFF + 2752512;                   // 11,534,336
static const size_t T8P_OFF = T3P_OFF;   // t8p (16.8MB) overlays t3p + tail

__device__ __forceinline__ void gl16(const f16* g, f16* l) {
  __builtin_amdgcn_global_load_lds((const __attribute__((address_space(1))) void*)g,
                                   (__attribute__((address_space(3))) void*)l, 16, 0, 0);
}

// ---------------------------------------------------------------- prepX: x -> xk AND xkTg (r6-proven)
// grid 984 = (kc*4+n)*82 + row; block 256
__global__ __launch_bounds__(256) void prepX_kernel(const float* __restrict__ x,
                                                    f16* __restrict__ xkT,
                                                    f16* __restrict__ xk) {
  __shared__ float T[128][65];
  unsigned b   = blockIdx.x;
  unsigned row = b % 82u;
  unsigned t2_ = b / 82u;
  unsigned n   = t2_ & 3u;
  unsigned kc  = t2_ >> 2;
  int hsrc = (int)row - 9;
  unsigned tid = threadIdx.x;
  unsigned w = tid & 63u, g = tid >> 6;
  f16* oT = xkT + (((size_t)(g * 3u + kc) * 4u + n) * 82u + row) * 2048u;
  f16* oX = xk + ((size_t)(kc * 4u + n) * 128u + (tid >> 1)) * XSTR + row * 64u + (tid & 1u) * 32u;

  if (hsrc >= 0 && hsrc < 64) {
    unsigned c = tid >> 1, half = (tid & 1u) * 32u;
    const float* src = x + ((size_t)(n * 128u + c) * 64u + (unsigned)hsrc) * 64u + half;
#pragma unroll
    for (int i = 0; i < 8; i++) {
      f32x4 v = *(const f32x4*)(src + i * 4);
      *(f32x4*)&T[c][half + (unsigned)i * 4u] = v;
    }
    __syncthreads();
    // xkTg: c-inner within own g-slice
    int wsrc = (int)w + 2 * (int)kc - 2;
    bool ok = (wsrc >= 0 && wsrc < 64);
#pragma unroll
    for (unsigned s = 0; s < 4u; s++) {
      f16x8 o;
#pragma unroll
      for (int i = 0; i < 8; i++)
        o[i] = ok ? (f16)(T[g * 32u + s * 8u + (unsigned)i][wsrc] * 0.125f) : (f16)0.f;
      *(f16x8*)(oT + w * 32u + s * 8u) = o;
    }
    // xk: w-inner
#pragma unroll
    for (unsigned s = 0; s < 4u; s++) {
      f16x8 o;
#pragma unroll
      for (int i = 0; i < 8; i++) {
        int ws = (int)(half + s * 8u + (unsigned)i) + 2 * (int)kc - 2;
        o[i] = (ws >= 0 && ws < 64) ? (f16)(T[c][ws] * 0.125f) : (f16)0.f;
      }
      *(f16x8*)(oX + s * 8u) = o;
    }
  } else {
    f16x8 z = {};
#pragma unroll
    for (unsigned s = 0; s < 4u; s++) *(f16x8*)(oT + w * 32u + s * 8u) = z;
#pragma unroll
    for (unsigned s = 0; s < 4u; s++) *(f16x8*)(oX + s * 8u) = z;
  }
}

// ---------------------------------------------------------------- prepPQ: q5Tg = (f16)(1+p5), g-major c-inner
// grid 1344 = rk*64 + h; block 256
__global__ __launch_bounds__(256) void prepPQ_kernel(const float* __restrict__ p5,
                                                     f16* __restrict__ q5T) {
  __shared__ float T[128][65];
  unsigned b  = blockIdx.x;
  unsigned h  = b & 63u;
  unsigned rk = b >> 6;
  unsigned tid = threadIdx.x;
  unsigned c = tid >> 1, half = (tid & 1u) * 32u;
  const float* src = p5 + ((size_t)c * 21u + rk) * 4096u + h * 64u + half;
#pragma unroll
  for (int i = 0; i < 8; i++) {
    f32x4 v = *(const f32x4*)(src + i * 4);
    *(f32x4*)&T[c][half + (unsigned)i * 4u] = v;
  }
  __syncthreads();
  unsigned w = tid & 63u, g = tid >> 6;
  f16* oplane = q5T + ((size_t)(g * 21u + rk) * 64u + h) * 2048u;
#pragma unroll
  for (unsigned s = 0; s < 4u; s++) {
    f16x8 o;
#pragma unroll
    for (int i = 0; i < 8; i++)
      o[i] = (f16)(1.0f + T[g * 32u + s * 8u + (unsigned)i][w]);
    *(f16x8*)(oplane + w * 32u + s * 8u) = o;
  }
}

// ---------------------------------------------------------------- gram (LDS-staged, rki 0..10, split-K)
// grid 704 = n(4)*rki(11)*cseg(2)*ks(8); block 256 (4 waves 2x2), tile 64c x 128d, K-slice 512, 8 steps.
__global__ __launch_bounds__(256, 3) void gram_kernel(const f16* __restrict__ xk,
                                                      f16* __restrict__ t3p) {
  __shared__ f16 gl[2 * 12288];

  unsigned b    = blockIdx.x;
  unsigned ks   = b & 7u;
  unsigned cseg = (b >> 3) & 1u;
  unsigned rki  = (b >> 4) % 11u;
  unsigned n    = b / 176u;
  unsigned r    = rki / 3u;
  unsigned kc   = rki - r * 3u;

  unsigned tid  = threadIdx.x;
  unsigned wv   = tid >> 6;
  unsigned lane = tid & 63u;
  unsigned wy   = wv >> 1;
  unsigned wx   = wv & 1u;
  unsigned quad = lane >> 4;
  unsigned l16  = lane & 15u;
  unsigned rsl  = lane >> 3;
  unsigned seg  = (lane & 7u) ^ (rsl & 7u);

  unsigned h0 = ks * 8u;
  const f16* Ab = xk + (size_t)(kc * 4u + n) * 128u * XSTR + (size_t)(cseg * 64u) * XSTR
                + (h0 + 3u * r) * 64u + seg * 8u;
  const f16* Bb = xk + (size_t)(4u + n) * 128u * XSTR + (h0 + 9u) * 64u + seg * 8u;
  unsigned ar0 = wv * 16u;
  unsigned br0 = wv * 32u;

  f32x4 acc[2][4] = {};

#pragma unroll
  for (unsigned t = 0; t < 2u; t++)
    gl16(Ab + (size_t)(ar0 + t * 8u + rsl) * XSTR, &gl[(ar0 + t * 8u) * 64u]);
#pragma unroll
  for (unsigned t = 0; t < 4u; t++)
    gl16(Bb + (size_t)(br0 + t * 8u + rsl) * XSTR, &gl[4096u + (br0 + t * 8u) * 64u]);

  for (unsigned s = 0; s < 8u; s++) {
    __syncthreads();
    if (s < 7u) {
      f16* base = &gl[((s + 1u) & 1u) * 12288u];
      unsigned off = (s + 1u) * 64u;
#pragma unroll
      for (unsigned t = 0; t < 2u; t++)
        gl16(Ab + off + (size_t)(ar0 + t * 8u + rsl) * XSTR, base + (ar0 + t * 8u) * 64u);
#pragma unroll
      for (unsigned t = 0; t < 4u; t++)
        gl16(Bb + off + (size_t)(br0 + t * 8u + rsl) * XSTR, base + 4096u + (br0 + t * 8u) * 64u);
    }
    const f16* bufA = &gl[(s & 1u) * 12288u];
    const f16* bufB = bufA + 4096u;
#pragma unroll
    for (unsigned t2 = 0; t2 < 2u; t2++) {
      unsigned L = t2 * 4u + quad;
      f16x8 a[2], bb[4];
#pragma unroll
      for (int ms = 0; ms < 2; ms++) {
        unsigned rr = wy * 32u + (unsigned)ms * 16u + l16;
        a[ms] = *(const f16x8*)&bufA[rr * 64u + (L ^ (rr & 7u)) * 8u];
      }
#pragma unroll
      for (int ns = 0; ns < 4; ns++) {
        unsigned rb = wx * 64u + (unsigned)ns * 16u + l16;
        bb[ns] = *(const f16x8*)&bufB[rb * 64u + (L ^ (rb & 7u)) * 8u];
      }
#pragma unroll
      for (int ms = 0; ms < 2; ms++)
#pragma unroll
        for (int ns = 0; ns < 4; ns++)
          acc[ms][ns] = __builtin_amdgcn_mfma_f32_16x16x32_f16(a[ms], bb[ns], acc[ms][ns], 0, 0, 0);
    }
  }

  f16* tp = t3p + ((size_t)(ks * 4u + n) * 11u + rki) * 16384u;
#pragma unroll
  for (int ms = 0; ms < 2; ms++) {
#pragma unroll
    for (int ns = 0; ns < 4; ns++) {
      unsigned c0 = cseg * 64u + wy * 32u + (unsigned)ms * 16u + quad * 4u;
      unsigned d  = wx * 64u + (unsigned)ns * 16u + l16;
#pragma unroll
      for (int reg = 0; reg < 4; reg++)
        tp[(size_t)(c0 + (unsigned)reg) * 128u + d] = (f16)acc[ms][ns][reg];
    }
  }
}

// ---------------------------------------------------------------- ep: t6T = p6 * t3 (mirror for rk>=11)
__global__ __launch_bounds__(256) void ep_kernel(const f16* __restrict__ t3p,
                                                 const float* __restrict__ p6,
                                                 f16* __restrict__ t6T) {
  unsigned idx = blockIdx.x * 256u + threadIdx.x;   // < 344064
  unsigned t   = idx >> 12;                          // n*21+rk
  unsigned rk  = t % 21u;
  unsigned n   = t / 21u;

  if (rk <= 10u) {
    unsigned d4 = idx & 31u;
    unsigned c  = (idx >> 5) & 127u;
    unsigned d0 = d4 * 4u;
    float s0 = 0.f, s1 = 0.f, s2 = 0.f, s3 = 0.f;
#pragma unroll
    for (unsigned ks = 0; ks < 8u; ks++) {
      f16x4 v = *(const f16x4*)(t3p + (((size_t)(ks * 4u + n) * 11u + rk) * 16384u + c * 128u + d0));
      s0 += (float)v[0]; s1 += (float)v[1]; s2 += (float)v[2]; s3 += (float)v[3];
    }
    const float* pp = p6 + ((size_t)c * 21u + rk) * 128u + d0;
    f16* ob = t6T + (size_t)(n * 128u + d0) * 2688u + rk * 128u + c;
    ob[0]        = (f16)(s0 * pp[0]);
    ob[2688]     = (f16)(s1 * pp[1]);
    ob[2 * 2688] = (f16)(s2 * pp[2]);
    ob[3 * 2688] = (f16)(s3 * pp[3]);
  } else {
    unsigned mrk = 20u - rk;          // t3[c,rk,d] = t3p_sum[mrk][d][c]
    unsigned c4 = idx & 31u;
    unsigned d  = (idx >> 5) & 127u;
    unsigned c0 = c4 * 4u;
    float s0 = 0.f, s1 = 0.f, s2 = 0.f, s3 = 0.f;
#pragma unroll
    for (unsigned ks = 0; ks < 8u; ks++) {
      f16x4 v = *(const f16x4*)(t3p + (((size_t)(ks * 4u + n) * 11u + mrk) * 16384u + d * 128u + c0));
      s0 += (float)v[0]; s1 += (float)v[1]; s2 += (float)v[2]; s3 += (float)v[3];
    }
    f16x4 o;
    o[0] = (f16)(s0 * p6[((size_t)(c0 + 0u) * 21u + rk) * 128u + d]);
    o[1] = (f16)(s1 * p6[((size_t)(c0 + 1u) * 21u + rk) * 128u + d]);
    o[2] = (f16)(s2 * p6[((size_t)(c0 + 2u) * 21u + rk) * 128u + d]);
    o[3] = (f16)(s3 * p6[((size_t)(c0 + 3u) * 21u + rk) * 128u + d]);
    *(f16x4*)(t6T + (size_t)(n * 128u + d) * 2688u + rk * 128u + c0) = o;
  }
}

// ---------------------------------------------------------------- outp (vectorized staging from g-major c-inner)
// grid 1024 = n(4)*h(64)*g(4); block 256 (4 waves 2x2), tile 64w x 128d, j 0..21.
// Staging per thread per chunk: 2 f16x8 vec loads (xkTg, q5Tg) + packed mul + ds_write_b128.
// (r12 lesson: 16 scalar staging loads serialize through a 56-VGPR budget — vector loads are atomic.)
#define ALDS_STR 40
#define RT_STR   72
__global__ __launch_bounds__(256, 4) void outp_kernel(const f16* __restrict__ xkT,
                                                      const f16* __restrict__ q5T,
                                                      const f16* __restrict__ t6T,
                                                      f16* __restrict__ t8p) {
  __shared__ f16 smem[128 * RT_STR];   // 18432 B; first 10240 B = 2 staging bufs
  f16* Alds = smem;

  unsigned b = blockIdx.x;
  unsigned g = b & 3u;
  unsigned h = (b >> 2) & 63u;
  unsigned n = b >> 8;

  unsigned tid  = threadIdx.x;
  unsigned wv   = tid >> 6;
  unsigned lane = tid & 63u;
  unsigned wy   = wv >> 1;
  unsigned wx   = wv & 1u;
  unsigned quad = lane >> 4;
  unsigned l16  = lane & 15u;
  unsigned sw   = tid >> 2;            // staging w (0..63)
  unsigned sc   = tid & 3u;            // staging c-octet (0..3)
  unsigned soff = sw * 32u + sc * 8u;  // offset within a 64w x 32c plane

  const f16* xgb = xkT + (size_t)(g * 3u) * 4u * 82u * 2048u;            // + ((kc*4+n)*82 + row)*2048
  const f16* qgb = q5T + (size_t)(g * 21u) * 64u * 2048u + (size_t)h * 2048u;  // + rk*64*2048
  const f16* bfb = t6T + (size_t)(n * 128u + wx * 64u + l16) * 2688u + g * 32u + quad * 8u;

  f32x4 acc[2][4] = {};
  f16x8 xa, qa, bfc[4];

  { // prefetch chunk 0 (rk=0 -> r=0, kc=0)
    xa = *(const f16x8*)(xgb + ((size_t)(0u * 4u + n) * 82u + h) * 2048u + soff);
    qa = *(const f16x8*)(qgb + soff);
#pragma unroll
    for (int ns = 0; ns < 4; ns++) bfc[ns] = *(const f16x8*)(bfb + (size_t)ns * 16u * 2688u);
  }

  for (unsigned j = 0; j < 21u; j++) {
    f16* Ag = Alds + (j & 1u) * 2560u;
    {
      f16x8 av = xa * qa;   // packed f16 mul (q5 = 1+p5 pre-folded)
      *(f16x8*)&Ag[sw * ALDS_STR + sc * 8u] = av;
    }
    __syncthreads();

    f16x8 xan, qan, bfn[4];
    if (j < 20u) {   // register prefetch of chunk j+1 (overlaps MFMA below)
      unsigned rk = j + 1u;
      unsigned rr = rk / 3u;
      unsigned kcc = rk - rr * 3u;
      xan = *(const f16x8*)(xgb + ((size_t)(kcc * 4u + n) * 82u + h + 3u * rr) * 2048u + soff);
      qan = *(const f16x8*)(qgb + (size_t)rk * 64u * 2048u + soff);
#pragma unroll
      for (int ns = 0; ns < 4; ns++) bfn[ns] = *(const f16x8*)(bfb + (size_t)ns * 16u * 2688u + rk * 128u);
    }

    f16x8 a[2];
#pragma unroll
    for (int ms = 0; ms < 2; ms++)
      a[ms] = *(const f16x8*)&Ag[(wy * 32u + (unsigned)ms * 16u + l16) * ALDS_STR + quad * 8u];
#pragma unroll
    for (int ms = 0; ms < 2; ms++)
#pragma unroll
      for (int ns = 0; ns < 4; ns++)
        acc[ms][ns] = __builtin_amdgcn_mfma_f32_16x16x32_f16(a[ms], bfc[ns], acc[ms][ns], 0, 0, 0);
    xa = xan; qa = qan;
#pragma unroll
    for (int ns = 0; ns < 4; ns++) bfc[ns] = bfn[ns];
  }

  // transpose via f16 LDS tile for coalesced partial stores: t8p[g][n][h][d][w]
  __syncthreads();
  f16* Rt = smem;
#pragma unroll
  for (int ms = 0; ms < 2; ms++)
#pragma unroll
    for (int ns = 0; ns < 4; ns++) {
      unsigned w0 = wy * 32u + (unsigned)ms * 16u + quad * 4u;
      unsigned d  = wx * 64u + (unsigned)ns * 16u + l16;
      f16x4 t;
#pragma unroll
      for (int reg = 0; reg < 4; reg++) t[reg] = (f16)acc[ms][ns][reg];
      *(f16x4*)&Rt[d * RT_STR + w0] = t;
    }
  __syncthreads();
  f16* op = t8p + ((size_t)((g * 4u + n) * 64u + h)) * 8192u;
#pragma unroll
  for (unsigned it = 0; it < 4u; it++) {
    unsigned row = (tid >> 3) + it * 32u;
    unsigned w0  = (tid & 7u) * 8u;
    f16x8 o = *(const f16x8*)&Rt[row * RT_STR + w0];
    *(f16x8*)(op + row * 64u + w0) = o;
  }
}

// ---------------------------------------------------------------- red: out = FS * sum_g(t8p), 4 slices
__global__ __launch_bounds__(256) void red_kernel(const f16* __restrict__ t8p,
                                                  float* __restrict__ out) {
  unsigned idx = blockIdx.x * 256u + threadIdx.x;
  unsigned w0 = (idx & 7u) * 8u;
  unsigned h  = (idx >> 3) & 63u;
  unsigned d  = (idx >> 9) & 127u;
  unsigned n  = idx >> 16;
  const float FS = 0.15430334996209192f;  // 8 / sqrt(2688)
  float s[8] = {};
#pragma unroll
  for (unsigned g = 0; g < 4u; g++) {
    f16x8 v = *(const f16x8*)(t8p + ((size_t)((g * 4u + n) * 64u + h)) * 8192u + d * 64u + w0);
#pragma unroll
    for (int i = 0; i < 8; i++) s[i] += (float)v[i];
  }
  f32x4 o0, o1;
#pragma unroll
  for (int i = 0; i < 4; i++) { o0[i] = s[i] * FS; o1[i] = s[i + 4] * FS; }
  float* op = out + ((size_t)(n * 128u + d) * 64u + h) * 64u + w0;
  *(f32x4*)op = o0;
  *(f32x4*)(op + 4) = o1;
}

// ---------------------------------------------------------------- launch
extern "C" void kernel_launch(void* const* d_in, const int* in_sizes, int n_in,
                              void* d_out, int out_size, void* d_ws, size_t ws_size,
                              hipStream_t stream) {
  const float* x  = (const float*)d_in[0];
  const float* p5 = (const float*)d_in[1];
  const float* p6 = (const float*)d_in[2];
  float* out = (float*)d_out;
  f16* xk  = (f16*)((char*)d_ws + XK_OFF);
  f16* xkT = (f16*)((char*)d_ws + XKT_OFF);
  f16* q5T = (f16*)((char*)d_ws + Q5T_OFF);
  f16* t6T = (f16*)((char*)d_ws + T6T_OFF);
  f16* t3p = (f16*)((char*)d_ws + T3P_OFF);
  f16* t8p = (f16*)((char*)d_ws + T8P_OFF);   // aliases t3p (dead after ep)

  hipLaunchKernelGGL(prepX_kernel,  dim3(984),  dim3(256), 0, stream, x, xkT, xk);
  hipLaunchKernelGGL(prepPQ_kernel, dim3(1344), dim3(256), 0, stream, p5, q5T);
  hipLaunchKernelGGL(gram_kernel,   dim3(704),  dim3(256), 0, stream, xk, t3p);
  hipLaunchKernelGGL(ep_kernel,     dim3(1344), dim3(256), 0, stream, t3p, p6, t6T);
  hipLaunchKernelGGL(outp_kernel,   dim3(1024), dim3(256), 0, stream, xkT, q5T, t6T, t8p);
  hipLaunchKernelGGL(red_kernel,    dim3(1024), dim3(256), 0, stream, t8p, out);
}